// Round 1
// 363.057 us; speedup vs baseline: 1.1444x; 1.1444x over previous
//
#include <hip/hip_runtime.h>

typedef __attribute__((ext_vector_type(8))) short short8;
typedef __attribute__((ext_vector_type(4))) float floatx4;

// int-bridge casts (generic->AS1/AS3): LDS generic addr low 32 bits = LDS offset
#define AS1(p) ((const __attribute__((address_space(1))) void*)(uintptr_t)(p))
#define AS3(p) ((__attribute__((address_space(3))) void*)(unsigned int)(uintptr_t)(p))

__device__ __forceinline__ unsigned short f2bf(float f) {
    union { float f; unsigned int u; } v; v.f = f;
    unsigned int u = v.u;
    unsigned int r = (u + 0x7FFFu + ((u >> 16) & 1u)) >> 16;
    return (unsigned short)r;
}

__device__ __forceinline__ int pk_bf16(float a, float b) {
#if __has_builtin(__builtin_amdgcn_cvt_pk_bf16_f32)
    auto r = __builtin_amdgcn_cvt_pk_bf16_f32(a, b);
    int out; __builtin_memcpy(&out, &r, sizeof(int)); return out;
#else
    return (int)f2bf(a) | ((int)f2bf(b) << 16);
#endif
}

// ---------------- convert x (fp32 -> bf16), 4 elems/thread ----------------
__global__ __launch_bounds__(256) void cvt_x(const float* __restrict__ src,
                                             unsigned short* __restrict__ dst, int n4) {
    int i = blockIdx.x * blockDim.x + threadIdx.x;
    if (i < n4) {
        float4 v = ((const float4*)src)[i];
        int2 o = {pk_bf16(v.x, v.y), pk_bf16(v.z, v.w)};
        ((int2*)dst)[i] = o;
    }
}

// ------------- transpose + convert: src[R][C] fp32 -> dst[C][R] bf16 -------------
__global__ __launch_bounds__(256) void transpose_bf16(const float* __restrict__ src,
                                                      unsigned short* __restrict__ dst,
                                                      int R, int C) {
    __shared__ float tile[32][33];
    int c0 = blockIdx.x * 32, r0 = blockIdx.y * 32;
    int tc = threadIdx.x & 31, tr = (threadIdx.x >> 5) * 4;
#pragma unroll
    for (int i = 0; i < 4; ++i)
        tile[tr + i][tc] = src[(size_t)(r0 + tr + i) * C + c0 + tc];
    __syncthreads();
#pragma unroll
    for (int i = 0; i < 4; ++i)
        dst[(size_t)(c0 + tr + i) * R + r0 + tc] = f2bf(tile[tc][tr + i]);
}

// ---------------- 256x256-tile ring-4 pipelined bf16 MFMA GEMM ----------------
// C[M][N] = A[M][K] * Bt[N][K]^T.  8 waves (2M x 4N), per-wave 128x64 output.
// BK=32, 4-slot LDS ring (128 KiB): compute tile t from slot t&3 while staging
// tile t+3 into slot (t+3)&3 == (t-1)&3 (reads of t-1 finished at its trailing
// barrier).  Counted s_waitcnt vmcnt(8) at tile end (= tiles t+2,t+3 in flight,
// 4 loads/thread/tile) -- never drains to 0 in the main loop (T3+T4).  Raw
// s_barrier (no implicit vmcnt-0 drain), s_setprio around MFMA clusters (T5),
// bijective XCD swizzle on a 1-D grid (T1; gridDim.x % 8 == 0).
// LDS chunk-XOR swizzle: chunk col c4 ^= (row>>1)&3, applied on the pre-swizzled
// GLOBAL source address (global_load_lds dest must stay linear) and on the
// ds_read address -- spreads a fragment-read's 64 lanes evenly over all 8
// 16B bank-groups.  Requires M%256==0, N%256==0, K%32==0, K>=96.
template <bool OUT_BF16>
__global__ __launch_bounds__(512, 2) void gemm_bt256(const unsigned short* __restrict__ A,
                                                     const unsigned short* __restrict__ Bt,
                                                     void* __restrict__ Cout,
                                                     int M, int N, int K, int nbx) {
    __shared__ unsigned short Al[4][256 * 32];
    __shared__ unsigned short Bl[4][256 * 32];

    const int tid = threadIdx.x;
    const int wave = tid >> 6, lane = tid & 63, quad = lane >> 4, l15 = lane & 15;
    const int wm = wave >> 2, wn = wave & 3;

    // XCD-aware bijective swizzle: launch id i -> XCD i%8 gets contiguous tiles.
    const int nwg = (int)gridDim.x;
    const int q8 = nwg >> 3;
    const int wgid = (int)blockIdx.x;
    const int swz = (wgid & 7) * q8 + (wgid >> 3);
    const int bm = (swz / nbx) * 256;
    const int bn = (swz % nbx) * 256;

    floatx4 acc[8][4];
    const floatx4 z = {0.f, 0.f, 0.f, 0.f};
#pragma unroll
    for (int mi = 0; mi < 8; ++mi)
#pragma unroll
        for (int ni = 0; ni < 4; ++ni) acc[mi][ni] = z;

    // Staging: each 256x32 tile = 1024 16B chunks; thread owns chunks tid, tid+512.
    // LDS chunk d holds global (row = d>>2, colchunk = (d&3) ^ ((d>>3)&3)).
    const int d0 = tid, d1 = tid + 512;
    const int r0 = d0 >> 2, c0 = ((d0 & 3) ^ ((d0 >> 3) & 3)) * 8;
    const int r1 = d1 >> 2, c1 = ((d1 & 3) ^ ((d1 >> 3) & 3)) * 8;
    const unsigned short* As0 = A + (size_t)(bm + r0) * K + c0;
    const unsigned short* As1 = A + (size_t)(bm + r1) * K + c1;
    const unsigned short* Bs0 = Bt + (size_t)(bn + r0) * K + c0;
    const unsigned short* Bs1 = Bt + (size_t)(bn + r1) * K + c1;

    auto stageA = [&](int t) {
        const int s = t & 3, ko = t * 32;
        __builtin_amdgcn_global_load_lds(AS1(As0 + ko), AS3(&Al[s][d0 * 8]), 16, 0, 0);
        __builtin_amdgcn_global_load_lds(AS1(As1 + ko), AS3(&Al[s][d1 * 8]), 16, 0, 0);
    };
    auto stageB = [&](int t) {
        const int s = t & 3, ko = t * 32;
        __builtin_amdgcn_global_load_lds(AS1(Bs0 + ko), AS3(&Bl[s][d0 * 8]), 16, 0, 0);
        __builtin_amdgcn_global_load_lds(AS1(Bs1 + ko), AS3(&Bl[s][d1 * 8]), 16, 0, 0);
    };

    // Fragment-read addressing.  row bits [1:0] come from l15 only, so the
    // swizzled column chunk (quad ^ ((row>>1)&3)) is mi/ni-independent.
    const int qc = (quad ^ ((l15 >> 1) & 3)) * 8;
    const int arow = wm * 128 + l15;
    const int brow = wn * 64 + l15;

    // ---- prologue: stage tiles 0,1,2; wait tile 0 (vmcnt 8 = tiles 1,2 in flight) ----
    stageA(0); stageB(0);
    stageA(1); stageB(1);
    stageA(2); stageB(2);
    asm volatile("s_waitcnt vmcnt(8)" ::: "memory");
    __builtin_amdgcn_s_barrier();

    const int NT = K >> 5;
    for (int t = 0; t < NT; ++t) {
        const int s = t & 3;
        const unsigned short* Alp = Al[s];
        const unsigned short* Blp = Bl[s];
        short8 af[4], bf[4];

        // ---- phase 1: mi 0..3 x ni 0..3 (8+4 ds_read_b128, stage A of t+3) ----
#pragma unroll
        for (int mi = 0; mi < 4; ++mi)
            af[mi] = *(const short8*)&Alp[(arow + mi * 16) * 32 + qc];
#pragma unroll
        for (int ni = 0; ni < 4; ++ni)
            bf[ni] = *(const short8*)&Blp[(brow + ni * 16) * 32 + qc];
        if (t + 3 < NT) stageA(t + 3);
        __builtin_amdgcn_s_barrier();
        __builtin_amdgcn_s_setprio(1);
#pragma unroll
        for (int mi = 0; mi < 4; ++mi)
#pragma unroll
            for (int ni = 0; ni < 4; ++ni)
                acc[mi][ni] = __builtin_amdgcn_mfma_f32_16x16x32_bf16(bf[ni], af[mi], acc[mi][ni], 0, 0, 0);
        __builtin_amdgcn_s_setprio(0);
        __builtin_amdgcn_s_barrier();

        // ---- phase 2: mi 4..7 x ni 0..3 (4 ds_read_b128, reuse bf, stage B of t+3) ----
#pragma unroll
        for (int mi = 0; mi < 4; ++mi)
            af[mi] = *(const short8*)&Alp[(arow + 64 + mi * 16) * 32 + qc];
        if (t + 3 < NT) stageB(t + 3);
        __builtin_amdgcn_s_barrier();
        __builtin_amdgcn_s_setprio(1);
#pragma unroll
        for (int mi = 0; mi < 4; ++mi)
#pragma unroll
            for (int ni = 0; ni < 4; ++ni)
                acc[4 + mi][ni] = __builtin_amdgcn_mfma_f32_16x16x32_bf16(bf[ni], af[mi], acc[4 + mi][ni], 0, 0, 0);
        __builtin_amdgcn_s_setprio(0);

        // ---- tile boundary: ensure tile t+1 resident before any wave reads it ----
        if (t + 3 < NT)      asm volatile("s_waitcnt vmcnt(8)" ::: "memory");
        else if (t + 2 < NT) asm volatile("s_waitcnt vmcnt(4)" ::: "memory");
        else if (t + 1 < NT) asm volatile("s_waitcnt vmcnt(0)" ::: "memory");
        __builtin_amdgcn_s_barrier();
    }

    // ---- epilogue: C^T fragment layout (row from A-frag, col = ni*16+quad*4+r) ----
#pragma unroll
    for (int mi = 0; mi < 8; ++mi) {
        const size_t row = (size_t)(bm + wm * 128 + mi * 16 + l15);
#pragma unroll
        for (int ni = 0; ni < 4; ++ni) {
            const size_t col = (size_t)(bn + wn * 64 + ni * 16 + quad * 4);
            if (OUT_BF16) {
                int2 val = {pk_bf16(acc[mi][ni][0], acc[mi][ni][1]),
                            pk_bf16(acc[mi][ni][2], acc[mi][ni][3])};
                *(int2*)((unsigned short*)Cout + row * N + col) = val;
            } else {
                *(float4*)((float*)Cout + row * N + col) = *(const float4*)&acc[mi][ni];
            }
        }
    }
}

// ---------------- sliding-window flash attention (S^T, 32q/wave) ----------------
// Grid (32 q-blocks of 128, 64 b*h). Block: 4 waves; wave w owns 32 queries.
// Wave-pair p = w>>1 active in chunks [p, p+4] of 6 (83% busy).
// S^T = K.Q^T; softmax stats per-lane (q=l15); P->A-frag via ds_bpermute.
// K/V double-buffered (stride 72: 2-way bank alias = free), reg-prefetched.
__global__ __launch_bounds__(256, 3) void attn_swin(const unsigned short* __restrict__ qkv,
                                                    unsigned short* __restrict__ attn_out) {
    __shared__ unsigned short Klds[2][64 * 72];
    __shared__ unsigned short Vtl[2][64 * 72];

    const int blk = blockIdx.x, bh = blockIdx.y;
    const int b = bh >> 4, h = bh & 15;
    const int tid = threadIdx.x;
    const int wave = tid >> 6, lane = tid & 63, quad = lane >> 4, l15 = lane & 15;
    const int pair = wave >> 1;            // diagonal band of the wave-pair
    const int qoff = (wave & 1) * 32;      // offset within the pair's 64-q band
    const int qi_base = blk * 128 + wave * 32;
    const size_t seqbase = (size_t)b * 4096;

    // Q fragments hoisted once (A-layout == B-layout of Q^T)
    short8 qf[2][2];
#pragma unroll
    for (int qt = 0; qt < 2; ++qt)
#pragma unroll
        for (int ks = 0; ks < 2; ++ks)
            qf[qt][ks] = *(const short8*)(qkv + (seqbase + qi_base + qt * 16 + l15) * 3072
                                          + h * 64 + ks * 32 + quad * 8);

    floatx4 o[2][4];  // [qt][dt]: lane holds O[q=qt*16+l15][d=dt*16+quad*4+r]
    const floatx4 z = {0.f, 0.f, 0.f, 0.f};
    float m_run[2], l_run[2];
#pragma unroll
    for (int qt = 0; qt < 2; ++qt) {
#pragma unroll
        for (int dt = 0; dt < 4; ++dt) o[qt][dt] = z;
        m_run[qt] = -1.0e30f; l_run[qt] = 0.f;
    }

    const int kwin0 = blk * 128 - 256;
    const int c0 = (blk >= 2) ? 0 : (4 - 2 * blk);
    const int cLo = pair, cHi = pair + 4;
    const int sk_key = tid >> 2, sk_g = (tid & 3) * 16;
    const int sv_key = tid & 63, sv_dg = (tid >> 6) * 16;
    const float SC = 0.18033688f;  // dh^-0.5 * log2(e)

    // bpermute lane addressing: src lane = (quad&1)*32 + (t>>1)*16 + l15
    const int addrA = (((quad & 1) << 5) + l15) << 2;
    const int addrB = addrA + 64;
    const bool hiq = quad >= 2;

    int4 kvreg[4];
    auto load_kv = [&](int k0) {
        const int4* sk = (const int4*)(qkv + (seqbase + k0 + sk_key) * 3072 + 1024 + h * 64 + sk_g);
        kvreg[0] = sk[0]; kvreg[1] = sk[1];
        const int4* sv = (const int4*)(qkv + (seqbase + k0 + sv_key) * 3072 + 2048 + h * 64 + sv_dg);
        kvreg[2] = sv[0]; kvreg[3] = sv[1];
    };
    auto write_kv = [&](int buf) {
        *(int4*)&Klds[buf][sk_key * 72 + sk_g]     = kvreg[0];
        *(int4*)&Klds[buf][sk_key * 72 + sk_g + 8] = kvreg[1];
        union { unsigned short s[16]; int4 q[2]; } t;
        t.q[0] = kvreg[2]; t.q[1] = kvreg[3];
#pragma unroll
        for (int i = 0; i < 16; ++i) Vtl[buf][(sv_dg + i) * 72 + sv_key] = t.s[i];
    };

    load_kv(kwin0 + c0 * 64);   // == key 0 for clipped blocks
    write_kv(0);

    for (int c = c0; c < 6; ++c) {
        const int buf = (c - c0) & 1;
        __syncthreads();
        if (c < 5) load_kv(kwin0 + (c + 1) * 64);  // prefetch overlaps compute

        if (c >= cLo && c <= cHi) {
#pragma unroll
            for (int qt = 0; qt < 2; ++qt) {
                // ---- S^T = K.Q^T (kf transient per qt to cap VGPR) ----
                floatx4 sT[4];
#pragma unroll
                for (int ni = 0; ni < 4; ++ni) sT[ni] = z;
#pragma unroll
                for (int ks = 0; ks < 2; ++ks) {
#pragma unroll
                    for (int ni = 0; ni < 4; ++ni) {
                        short8 kf = *(const short8*)&Klds[buf][(ni * 16 + l15) * 72 + ks * 32 + quad * 8];
                        sT[ni] = __builtin_amdgcn_mfma_f32_16x16x32_bf16(kf, qf[qt][ks], sT[ni], 0, 0, 0);
                    }
                }

                // ---- V^T fragments early (latency hidden under softmax VALU) ----
                short8 vf[4][2];
#pragma unroll
                for (int dt = 0; dt < 4; ++dt)
#pragma unroll
                    for (int ks = 0; ks < 2; ++ks)
                        vf[dt][ks] = *(const short8*)&Vtl[buf][(dt * 16 + l15) * 72 + ks * 32 + quad * 8];

                // ---- mask diagonal chunks (key j = ni*16+quad*4+r, query i64) ----
                const int i64 = qoff + qt * 16 + l15;
                if (c == cLo) {            // valid iff j >= i64+1
#pragma unroll
                    for (int ni = 0; ni < 4; ++ni) {
                        int jb = ni * 16 + quad * 4;
#pragma unroll
                        for (int r = 0; r < 4; ++r)
                            if (jb + r < i64 + 1) sT[ni][r] = -3.0e38f;
                    }
                } else if (c == cHi) {     // valid iff j <= i64
#pragma unroll
                    for (int ni = 0; ni < 4; ++ni) {
                        int jb = ni * 16 + quad * 4;
#pragma unroll
                        for (int r = 0; r < 4; ++r)
                            if (jb + r > i64) sT[ni][r] = -3.0e38f;
                    }
                }

                // ---- online softmax (log2 domain, per-lane stats) ----
                float mx = -3.0e38f;
#pragma unroll
                for (int ni = 0; ni < 4; ++ni)
#pragma unroll
                    for (int r = 0; r < 4; ++r) mx = fmaxf(mx, sT[ni][r]);
                mx = fmaxf(mx, __shfl_xor(mx, 16));
                mx = fmaxf(mx, __shfl_xor(mx, 32));
                float mn = fmaxf(m_run[qt], mx * SC);
                float alpha = __builtin_amdgcn_exp2f(m_run[qt] - mn);
                m_run[qt] = mn;

                float ls = 0.f;
                int Pk[4][2];
#pragma unroll
                for (int ni = 0; ni < 4; ++ni) {
                    float p0 = __builtin_amdgcn_exp2f(fmaf(sT[ni][0], SC, -mn));
                    float p1 = __builtin_amdgcn_exp2f(fmaf(sT[ni][1], SC, -mn));
                    float p2 = __builtin_amdgcn_exp2f(fmaf(sT[ni][2], SC, -mn));
                    float p3 = __builtin_amdgcn_exp2f(fmaf(sT[ni][3], SC, -mn));
                    ls += (p0 + p1) + (p2 + p3);
                    Pk[ni][0] = pk_bf16(p0, p1);
                    Pk[ni][1] = pk_bf16(p2, p3);
                }
                ls += __shfl_xor(ls, 16);
                ls += __shfl_xor(ls, 32);
                l_run[qt] = l_run[qt] * alpha + ls;
#pragma unroll
                for (int dt = 0; dt < 4; ++dt)
#pragma unroll
                    for (int r = 0; r < 4; ++r) o[qt][dt][r] *= alpha;

                // ---- quad-permute P (C-layout) -> A-frag, then PV ----
#pragma unroll
                for (int ks = 0; ks < 2; ++ks) {
                    int a0 = __builtin_amdgcn_ds_bpermute(addrA, Pk[2 * ks][0]);
                    int b0 = __builtin_amdgcn_ds_bpermute(addrA, Pk[2 * ks + 1][0]);
                    int a1 = __builtin_amdgcn_ds_bpermute(addrA, Pk[2 * ks][1]);
                    int b1 = __builtin_amdgcn_ds_bpermute(addrA, Pk[2 * ks + 1][1]);
                    int a2 = __builtin_amdgcn_ds_bpermute(addrB, Pk[2 * ks][0]);
                    int b2 = __builtin_amdgcn_ds_bpermute(addrB, Pk[2 * ks + 1][0]);
                    int a3 = __builtin_amdgcn_ds_bpermute(addrB, Pk[2 * ks][1]);
                    int b3 = __builtin_amdgcn_ds_bpermute(addrB, Pk[2 * ks + 1][1]);
                    union { int i[4]; short8 v; } u;
                    u.i[0] = hiq ? b0 : a0;
                    u.i[1] = hiq ? b1 : a1;
                    u.i[2] = hiq ? b2 : a2;
                    u.i[3] = hiq ? b3 : a3;
#pragma unroll
                    for (int dt = 0; dt < 4; ++dt)
                        o[qt][dt] = __builtin_amdgcn_mfma_f32_16x16x32_bf16(vf[dt][ks], u.v, o[qt][dt], 0, 0, 0);
                }
            }
        }

        if (c < 5) write_kv(buf ^ 1);
    }

    // ---- epilogue ----
#pragma unroll
    for (int qt = 0; qt < 2; ++qt) {
        float rl = __builtin_amdgcn_rcpf(l_run[qt]);
        size_t rowb = (seqbase + qi_base + qt * 16 + l15) * 1024 + h * 64;
#pragma unroll
        for (int dt = 0; dt < 4; ++dt) {
            int2 val = {pk_bf16(o[qt][dt][0] * rl, o[qt][dt][1] * rl),
                        pk_bf16(o[qt][dt][2] * rl, o[qt][dt][3] * rl)};
            *(int2*)(attn_out + rowb + dt * 16 + quad * 4) = val;
        }
    }
}

extern "C" void kernel_launch(void* const* d_in, const int* in_sizes, int n_in,
                              void* d_out, int out_size, void* d_ws, size_t ws_size,
                              hipStream_t stream) {
    const float* x     = (const float*)d_in[0];  // [4,4096,1024]
    const float* w_qkv = (const float*)d_in[1];  // [1024,3072]
    const float* w_out = (const float*)d_in[2];  // [1024,1024]
    float* out = (float*)d_out;                  // [4,4096,1024]

    unsigned short* xb    = (unsigned short*)d_ws;                 // 16384*1024
    unsigned short* wqkvT = xb    + (size_t)16384 * 1024;          // 3072*1024
    unsigned short* woutT = wqkvT + (size_t)3072 * 1024;           // 1024*1024
    unsigned short* qkv   = woutT + (size_t)1024 * 1024;           // 16384*3072
    unsigned short* attn  = qkv   + (size_t)16384 * 3072;          // 16384*1024

    cvt_x<<<16384, 256, 0, stream>>>(x, xb, 4194304);
    transpose_bf16<<<dim3(96, 32), 256, 0, stream>>>(w_qkv, wqkvT, 1024, 3072);
    transpose_bf16<<<dim3(32, 32), 256, 0, stream>>>(w_out, woutT, 1024, 1024);
    // QKV: M=16384, N=3072 -> 64x12 = 768 tiles (768 % 8 == 0)
    gemm_bt256<true><<<768, 512, 0, stream>>>(xb, wqkvT, qkv, 16384, 3072, 1024, 12);
    attn_swin<<<dim3(32, 64), 256, 0, stream>>>(qkv, attn);
    // out-proj: M=16384, N=1024 -> 64x4 = 256 tiles (256 % 8 == 0)
    gemm_bt256<false><<<256, 512, 0, stream>>>(attn, woutT, out, 16384, 1024, 1024, 4);
}

// Round 2
// 362.397 us; speedup vs baseline: 1.1465x; 1.0018x over previous
//
#include <hip/hip_runtime.h>

typedef __attribute__((ext_vector_type(8))) short short8;
typedef __attribute__((ext_vector_type(4))) float floatx4;

// int-bridge casts (generic->AS1/AS3): LDS generic addr low 32 bits = LDS offset
#define AS1(p) ((const __attribute__((address_space(1))) void*)(uintptr_t)(p))
#define AS3(p) ((__attribute__((address_space(3))) void*)(unsigned int)(uintptr_t)(p))

__device__ __forceinline__ unsigned short f2bf(float f) {
    union { float f; unsigned int u; } v; v.f = f;
    unsigned int u = v.u;
    unsigned int r = (u + 0x7FFFu + ((u >> 16) & 1u)) >> 16;
    return (unsigned short)r;
}

__device__ __forceinline__ int pk_bf16(float a, float b) {
#if __has_builtin(__builtin_amdgcn_cvt_pk_bf16_f32)
    auto r = __builtin_amdgcn_cvt_pk_bf16_f32(a, b);
    int out; __builtin_memcpy(&out, &r, sizeof(int)); return out;
#else
    return (int)f2bf(a) | ((int)f2bf(b) << 16);
#endif
}

// ---------------- convert x (fp32 -> bf16), 4 elems/thread ----------------
__global__ __launch_bounds__(256) void cvt_x(const float* __restrict__ src,
                                             unsigned short* __restrict__ dst, int n4) {
    int i = blockIdx.x * blockDim.x + threadIdx.x;
    if (i < n4) {
        float4 v = ((const float4*)src)[i];
        int2 o = {pk_bf16(v.x, v.y), pk_bf16(v.z, v.w)};
        ((int2*)dst)[i] = o;
    }
}

// ------------- transpose + convert: src[R][C] fp32 -> dst[C][R] bf16 -------------
__global__ __launch_bounds__(256) void transpose_bf16(const float* __restrict__ src,
                                                      unsigned short* __restrict__ dst,
                                                      int R, int C) {
    __shared__ float tile[32][33];
    int c0 = blockIdx.x * 32, r0 = blockIdx.y * 32;
    int tc = threadIdx.x & 31, tr = (threadIdx.x >> 5) * 4;
#pragma unroll
    for (int i = 0; i < 4; ++i)
        tile[tr + i][tc] = src[(size_t)(r0 + tr + i) * C + c0 + tc];
    __syncthreads();
#pragma unroll
    for (int i = 0; i < 4; ++i)
        dst[(size_t)(c0 + tr + i) * R + r0 + tc] = f2bf(tile[tc][tr + i]);
}

// ---------------- 256x256-tile ring-4 pipelined bf16 MFMA GEMM ----------------
// C[M][N] = A[M][K] * Bt[N][K]^T.  8 waves (2M x 4N), per-wave 128x64 output.
// BK=32, 4-slot LDS ring (128 KiB): compute tile t from slot t&3 while staging
// tile t+3 into slot (t+3)&3 == (t-1)&3.  Counted vmcnt (never 0 mid-loop).
// Fine interleave (m196 lever): frag reads are software-pipelined so the LDS
// pipe drains UNDER the MFMA clusters --
//   phase 1: stageA(t+3) + read af1 (phase-2 A-frags)  -> MFMA Q0 (uses regs
//            read last tile; compiler emits counted lgkmcnt(4))
//   mid:     vmcnt(6) + barrier  (publishes tile t+1 residency early)
//   phase 2: read NEXT tile's Q0 frags + stageB(t+3)   -> MFMA Q1
//   end:     barrier (closes WAR window before staging into slot (t-1)&3)
// Frag double-buffering via explicit x2 unroll (static register sets).
// Requires M%256==0, N%256==0, K%32==0, K>=96, (K/32) even.
template <bool OUT_BF16>
__global__ __launch_bounds__(512, 2) void gemm_bt256(const unsigned short* __restrict__ A,
                                                     const unsigned short* __restrict__ Bt,
                                                     void* __restrict__ Cout,
                                                     int M, int N, int K, int nbx) {
    __shared__ unsigned short Al[4][256 * 32];
    __shared__ unsigned short Bl[4][256 * 32];

    const int tid = threadIdx.x;
    const int wave = tid >> 6, lane = tid & 63, quad = lane >> 4, l15 = lane & 15;
    const int wm = wave >> 2, wn = wave & 3;

    // XCD-aware bijective swizzle: launch id i -> XCD i%8 gets contiguous tiles.
    const int nwg = (int)gridDim.x;
    const int q8 = nwg >> 3;
    const int wgid = (int)blockIdx.x;
    const int swz = (wgid & 7) * q8 + (wgid >> 3);
    const int bm = (swz / nbx) * 256;
    const int bn = (swz % nbx) * 256;

    floatx4 acc[8][4];
    const floatx4 z = {0.f, 0.f, 0.f, 0.f};
#pragma unroll
    for (int mi = 0; mi < 8; ++mi)
#pragma unroll
        for (int ni = 0; ni < 4; ++ni) acc[mi][ni] = z;

    // Staging: each 256x32 tile = 1024 16B chunks; thread owns chunks tid, tid+512.
    // LDS chunk d holds global (row = d>>2, colchunk = (d&3) ^ ((d>>3)&3)).
    const int d0 = tid, d1 = tid + 512;
    const int r0 = d0 >> 2, c0 = ((d0 & 3) ^ ((d0 >> 3) & 3)) * 8;
    const int r1 = d1 >> 2, c1 = ((d1 & 3) ^ ((d1 >> 3) & 3)) * 8;
    const unsigned short* As0 = A + (size_t)(bm + r0) * K + c0;
    const unsigned short* As1 = A + (size_t)(bm + r1) * K + c1;
    const unsigned short* Bs0 = Bt + (size_t)(bn + r0) * K + c0;
    const unsigned short* Bs1 = Bt + (size_t)(bn + r1) * K + c1;

    const int NT = K >> 5;

    auto stageA = [&](int t) {
        const int s = t & 3, ko = t * 32;
        __builtin_amdgcn_global_load_lds(AS1(As0 + ko), AS3(&Al[s][d0 * 8]), 16, 0, 0);
        __builtin_amdgcn_global_load_lds(AS1(As1 + ko), AS3(&Al[s][d1 * 8]), 16, 0, 0);
    };
    auto stageB = [&](int t) {
        const int s = t & 3, ko = t * 32;
        __builtin_amdgcn_global_load_lds(AS1(Bs0 + ko), AS3(&Bl[s][d0 * 8]), 16, 0, 0);
        __builtin_amdgcn_global_load_lds(AS1(Bs1 + ko), AS3(&Bl[s][d1 * 8]), 16, 0, 0);
    };

    // Fragment-read addressing.  row bits [1:0] come from l15 only, so the
    // swizzled column chunk (quad ^ ((row>>1)&3)) is mi/ni-independent.
    const int qc = (quad ^ ((l15 >> 1) & 3)) * 8;
    const int arow = wm * 128 + l15;
    const int brow = wn * 64 + l15;

    // ---- prologue: stage tiles 0,1,2; wait tile 0 (vmcnt 8 = tiles 1,2 in flight) ----
    stageA(0); stageB(0);
    stageA(1); stageB(1);
    stageA(2); stageB(2);
    asm volatile("s_waitcnt vmcnt(8)" ::: "memory");
    __builtin_amdgcn_s_barrier();

    short8 afA[4], bfA[4], afB[4], bfB[4];
    // preload tile 0's Q0 fragments
#pragma unroll
    for (int mi = 0; mi < 4; ++mi)
        afA[mi] = *(const short8*)&Al[0][(arow + mi * 16) * 32 + qc];
#pragma unroll
    for (int ni = 0; ni < 4; ++ni)
        bfA[ni] = *(const short8*)&Bl[0][(brow + ni * 16) * 32 + qc];

    // Tile body: cur frags already in (caf,cbf); reads next tile's Q0 into (naf,nbf).
    auto body = [&](int t, short8 (&caf)[4], short8 (&cbf)[4],
                    short8 (&naf)[4], short8 (&nbf)[4]) {
        const int s = t & 3;
        const unsigned short* Alp = Al[s];
        if (t + 3 < NT) stageA(t + 3);
        short8 af1[4];
#pragma unroll
        for (int mi = 0; mi < 4; ++mi)
            af1[mi] = *(const short8*)&Alp[(arow + 64 + mi * 16) * 32 + qc];
        // MFMA Q0: operands were read last tile (counted lgkmcnt; af1 drains under it)
        __builtin_amdgcn_s_setprio(1);
#pragma unroll
        for (int mi = 0; mi < 4; ++mi)
#pragma unroll
            for (int ni = 0; ni < 4; ++ni)
                acc[mi][ni] = __builtin_amdgcn_mfma_f32_16x16x32_bf16(cbf[ni], caf[mi], acc[mi][ni], 0, 0, 0);
        __builtin_amdgcn_s_setprio(0);
        // publish tile t+1 residency (counted: tiles t+2, t+3A may stay in flight)
        if (t + 3 < NT)       asm volatile("s_waitcnt vmcnt(6)" ::: "memory");
        else if (t + 3 == NT) asm volatile("s_waitcnt vmcnt(4)" ::: "memory");
        else                  asm volatile("s_waitcnt vmcnt(0)" ::: "memory");
        __builtin_amdgcn_s_barrier();
        if (t + 1 < NT) {
            const unsigned short* Aln = Al[(t + 1) & 3];
            const unsigned short* Bln = Bl[(t + 1) & 3];
#pragma unroll
            for (int mi = 0; mi < 4; ++mi)
                naf[mi] = *(const short8*)&Aln[(arow + mi * 16) * 32 + qc];
#pragma unroll
            for (int ni = 0; ni < 4; ++ni)
                nbf[ni] = *(const short8*)&Bln[(brow + ni * 16) * 32 + qc];
        }
        if (t + 3 < NT) stageB(t + 3);
        // MFMA Q1: uses af1 (counted lgkmcnt; next-tile reads drain under it)
        __builtin_amdgcn_s_setprio(1);
#pragma unroll
        for (int mi = 0; mi < 4; ++mi)
#pragma unroll
            for (int ni = 0; ni < 4; ++ni)
                acc[4 + mi][ni] = __builtin_amdgcn_mfma_f32_16x16x32_bf16(cbf[ni], af1[mi], acc[4 + mi][ni], 0, 0, 0);
        __builtin_amdgcn_s_setprio(0);
        __builtin_amdgcn_s_barrier();   // WAR close: slot (t-1)&3 may be re-staged next
    };

    for (int tt = 0; tt < NT; tt += 2) {
        body(tt,     afA, bfA, afB, bfB);
        body(tt + 1, afB, bfB, afA, bfA);
    }

    // ---- epilogue: C^T fragment layout (row from A-frag, col = ni*16+quad*4+r) ----
#pragma unroll
    for (int mi = 0; mi < 8; ++mi) {
        const size_t row = (size_t)(bm + wm * 128 + mi * 16 + l15);
#pragma unroll
        for (int ni = 0; ni < 4; ++ni) {
            const size_t col = (size_t)(bn + wn * 64 + ni * 16 + quad * 4);
            if (OUT_BF16) {
                int2 val = {pk_bf16(acc[mi][ni][0], acc[mi][ni][1]),
                            pk_bf16(acc[mi][ni][2], acc[mi][ni][3])};
                *(int2*)((unsigned short*)Cout + row * N + col) = val;
            } else {
                *(float4*)((float*)Cout + row * N + col) = *(const float4*)&acc[mi][ni];
            }
        }
    }
}

// ---------------- sliding-window flash attention (S^T, 32q/wave) ----------------
// Grid (32 q-blocks of 128, 64 b*h). Block: 4 waves; wave w owns 32 queries.
// Wave-pair p = w>>1 active in chunks [p, p+4] of 6 (83% busy).
// S^T = K.Q^T; softmax stats per-lane (q=l15); P->A-frag via ds_bpermute.
// K/V double-buffered (stride 72: 2-way bank alias = free), reg-prefetched.
__global__ __launch_bounds__(256, 3) void attn_swin(const unsigned short* __restrict__ qkv,
                                                    unsigned short* __restrict__ attn_out) {
    __shared__ unsigned short Klds[2][64 * 72];
    __shared__ unsigned short Vtl[2][64 * 72];

    const int blk = blockIdx.x, bh = blockIdx.y;
    const int b = bh >> 4, h = bh & 15;
    const int tid = threadIdx.x;
    const int wave = tid >> 6, lane = tid & 63, quad = lane >> 4, l15 = lane & 15;
    const int pair = wave >> 1;            // diagonal band of the wave-pair
    const int qoff = (wave & 1) * 32;      // offset within the pair's 64-q band
    const int qi_base = blk * 128 + wave * 32;
    const size_t seqbase = (size_t)b * 4096;

    // Q fragments hoisted once (A-layout == B-layout of Q^T)
    short8 qf[2][2];
#pragma unroll
    for (int qt = 0; qt < 2; ++qt)
#pragma unroll
        for (int ks = 0; ks < 2; ++ks)
            qf[qt][ks] = *(const short8*)(qkv + (seqbase + qi_base + qt * 16 + l15) * 3072
                                          + h * 64 + ks * 32 + quad * 8);

    floatx4 o[2][4];  // [qt][dt]: lane holds O[q=qt*16+l15][d=dt*16+quad*4+r]
    const floatx4 z = {0.f, 0.f, 0.f, 0.f};
    float m_run[2], l_run[2];
#pragma unroll
    for (int qt = 0; qt < 2; ++qt) {
#pragma unroll
        for (int dt = 0; dt < 4; ++dt) o[qt][dt] = z;
        m_run[qt] = -1.0e30f; l_run[qt] = 0.f;
    }

    const int kwin0 = blk * 128 - 256;
    const int c0 = (blk >= 2) ? 0 : (4 - 2 * blk);
    const int cLo = pair, cHi = pair + 4;
    const int sk_key = tid >> 2, sk_g = (tid & 3) * 16;
    const int sv_key = tid & 63, sv_dg = (tid >> 6) * 16;
    const float SC = 0.18033688f;  // dh^-0.5 * log2(e)

    // bpermute lane addressing: src lane = (quad&1)*32 + (t>>1)*16 + l15
    const int addrA = (((quad & 1) << 5) + l15) << 2;
    const int addrB = addrA + 64;
    const bool hiq = quad >= 2;

    int4 kvreg[4];
    auto load_kv = [&](int k0) {
        const int4* sk = (const int4*)(qkv + (seqbase + k0 + sk_key) * 3072 + 1024 + h * 64 + sk_g);
        kvreg[0] = sk[0]; kvreg[1] = sk[1];
        const int4* sv = (const int4*)(qkv + (seqbase + k0 + sv_key) * 3072 + 2048 + h * 64 + sv_dg);
        kvreg[2] = sv[0]; kvreg[3] = sv[1];
    };
    auto write_kv = [&](int buf) {
        *(int4*)&Klds[buf][sk_key * 72 + sk_g]     = kvreg[0];
        *(int4*)&Klds[buf][sk_key * 72 + sk_g + 8] = kvreg[1];
        union { unsigned short s[16]; int4 q[2]; } t;
        t.q[0] = kvreg[2]; t.q[1] = kvreg[3];
#pragma unroll
        for (int i = 0; i < 16; ++i) Vtl[buf][(sv_dg + i) * 72 + sv_key] = t.s[i];
    };

    load_kv(kwin0 + c0 * 64);   // == key 0 for clipped blocks
    write_kv(0);

    for (int c = c0; c < 6; ++c) {
        const int buf = (c - c0) & 1;
        __syncthreads();
        if (c < 5) load_kv(kwin0 + (c + 1) * 64);  // prefetch overlaps compute

        if (c >= cLo && c <= cHi) {
#pragma unroll
            for (int qt = 0; qt < 2; ++qt) {
                // ---- S^T = K.Q^T (kf transient per qt to cap VGPR) ----
                floatx4 sT[4];
#pragma unroll
                for (int ni = 0; ni < 4; ++ni) sT[ni] = z;
#pragma unroll
                for (int ks = 0; ks < 2; ++ks) {
#pragma unroll
                    for (int ni = 0; ni < 4; ++ni) {
                        short8 kf = *(const short8*)&Klds[buf][(ni * 16 + l15) * 72 + ks * 32 + quad * 8];
                        sT[ni] = __builtin_amdgcn_mfma_f32_16x16x32_bf16(kf, qf[qt][ks], sT[ni], 0, 0, 0);
                    }
                }

                // ---- V^T fragments early (latency hidden under softmax VALU) ----
                short8 vf[4][2];
#pragma unroll
                for (int dt = 0; dt < 4; ++dt)
#pragma unroll
                    for (int ks = 0; ks < 2; ++ks)
                        vf[dt][ks] = *(const short8*)&Vtl[buf][(dt * 16 + l15) * 72 + ks * 32 + quad * 8];

                // ---- mask diagonal chunks (key j = ni*16+quad*4+r, query i64) ----
                const int i64 = qoff + qt * 16 + l15;
                if (c == cLo) {            // valid iff j >= i64+1
#pragma unroll
                    for (int ni = 0; ni < 4; ++ni) {
                        int jb = ni * 16 + quad * 4;
#pragma unroll
                        for (int r = 0; r < 4; ++r)
                            if (jb + r < i64 + 1) sT[ni][r] = -3.0e38f;
                    }
                } else if (c == cHi) {     // valid iff j <= i64
#pragma unroll
                    for (int ni = 0; ni < 4; ++ni) {
                        int jb = ni * 16 + quad * 4;
#pragma unroll
                        for (int r = 0; r < 4; ++r)
                            if (jb + r > i64) sT[ni][r] = -3.0e38f;
                    }
                }

                // ---- online softmax (log2 domain, per-lane stats) ----
                float mx = -3.0e38f;
#pragma unroll
                for (int ni = 0; ni < 4; ++ni)
#pragma unroll
                    for (int r = 0; r < 4; ++r) mx = fmaxf(mx, sT[ni][r]);
                mx = fmaxf(mx, __shfl_xor(mx, 16));
                mx = fmaxf(mx, __shfl_xor(mx, 32));
                float mn = fmaxf(m_run[qt], mx * SC);
                float alpha = __builtin_amdgcn_exp2f(m_run[qt] - mn);
                m_run[qt] = mn;

                float ls = 0.f;
                int Pk[4][2];
#pragma unroll
                for (int ni = 0; ni < 4; ++ni) {
                    float p0 = __builtin_amdgcn_exp2f(fmaf(sT[ni][0], SC, -mn));
                    float p1 = __builtin_amdgcn_exp2f(fmaf(sT[ni][1], SC, -mn));
                    float p2 = __builtin_amdgcn_exp2f(fmaf(sT[ni][2], SC, -mn));
                    float p3 = __builtin_amdgcn_exp2f(fmaf(sT[ni][3], SC, -mn));
                    ls += (p0 + p1) + (p2 + p3);
                    Pk[ni][0] = pk_bf16(p0, p1);
                    Pk[ni][1] = pk_bf16(p2, p3);
                }
                ls += __shfl_xor(ls, 16);
                ls += __shfl_xor(ls, 32);
                l_run[qt] = l_run[qt] * alpha + ls;
#pragma unroll
                for (int dt = 0; dt < 4; ++dt)
#pragma unroll
                    for (int r = 0; r < 4; ++r) o[qt][dt][r] *= alpha;

                // ---- quad-permute P (C-layout) -> A-frag, then PV ----
#pragma unroll
                for (int ks = 0; ks < 2; ++ks) {
                    int a0 = __builtin_amdgcn_ds_bpermute(addrA, Pk[2 * ks][0]);
                    int b0 = __builtin_amdgcn_ds_bpermute(addrA, Pk[2 * ks + 1][0]);
                    int a1 = __builtin_amdgcn_ds_bpermute(addrA, Pk[2 * ks][1]);
                    int b1 = __builtin_amdgcn_ds_bpermute(addrA, Pk[2 * ks + 1][1]);
                    int a2 = __builtin_amdgcn_ds_bpermute(addrB, Pk[2 * ks][0]);
                    int b2 = __builtin_amdgcn_ds_bpermute(addrB, Pk[2 * ks + 1][0]);
                    int a3 = __builtin_amdgcn_ds_bpermute(addrB, Pk[2 * ks][1]);
                    int b3 = __builtin_amdgcn_ds_bpermute(addrB, Pk[2 * ks + 1][1]);
                    union { int i[4]; short8 v; } u;
                    u.i[0] = hiq ? b0 : a0;
                    u.i[1] = hiq ? b1 : a1;
                    u.i[2] = hiq ? b2 : a2;
                    u.i[3] = hiq ? b3 : a3;
#pragma unroll
                    for (int dt = 0; dt < 4; ++dt)
                        o[qt][dt] = __builtin_amdgcn_mfma_f32_16x16x32_bf16(vf[dt][ks], u.v, o[qt][dt], 0, 0, 0);
                }
            }
        }

        if (c < 5) write_kv(buf ^ 1);
    }

    // ---- epilogue ----
#pragma unroll
    for (int qt = 0; qt < 2; ++qt) {
        float rl = __builtin_amdgcn_rcpf(l_run[qt]);
        size_t rowb = (seqbase + qi_base + qt * 16 + l15) * 1024 + h * 64;
#pragma unroll
        for (int dt = 0; dt < 4; ++dt) {
            int2 val = {pk_bf16(o[qt][dt][0] * rl, o[qt][dt][1] * rl),
                        pk_bf16(o[qt][dt][2] * rl, o[qt][dt][3] * rl)};
            *(int2*)(attn_out + rowb + dt * 16 + quad * 4) = val;
        }
    }
}

extern "C" void kernel_launch(void* const* d_in, const int* in_sizes, int n_in,
                              void* d_out, int out_size, void* d_ws, size_t ws_size,
                              hipStream_t stream) {
    const float* x     = (const float*)d_in[0];  // [4,4096,1024]
    const float* w_qkv = (const float*)d_in[1];  // [1024,3072]
    const float* w_out = (const float*)d_in[2];  // [1024,1024]
    float* out = (float*)d_out;                  // [4,4096,1024]

    unsigned short* xb    = (unsigned short*)d_ws;                 // 16384*1024
    unsigned short* wqkvT = xb    + (size_t)16384 * 1024;          // 3072*1024
    unsigned short* woutT = wqkvT + (size_t)3072 * 1024;           // 1024*1024
    unsigned short* qkv   = woutT + (size_t)1024 * 1024;           // 16384*3072
    unsigned short* attn  = qkv   + (size_t)16384 * 3072;          // 16384*1024

    cvt_x<<<16384, 256, 0, stream>>>(x, xb, 4194304);
    transpose_bf16<<<dim3(96, 32), 256, 0, stream>>>(w_qkv, wqkvT, 1024, 3072);
    transpose_bf16<<<dim3(32, 32), 256, 0, stream>>>(w_out, woutT, 1024, 1024);
    // QKV: M=16384, N=3072 -> 64x12 = 768 tiles (768 % 8 == 0)
    gemm_bt256<true><<<768, 512, 0, stream>>>(xb, wqkvT, qkv, 16384, 3072, 1024, 12);
    attn_swin<<<dim3(32, 64), 256, 0, stream>>>(qkv, attn);
    // out-proj: M=16384, N=1024 -> 64x4 = 256 tiles (256 % 8 == 0)
    gemm_bt256<false><<<256, 512, 0, stream>>>(attn, woutT, out, 16384, 1024, 1024, 4);
}

// Round 3
// 360.956 us; speedup vs baseline: 1.1511x; 1.0040x over previous
//
#include <hip/hip_runtime.h>

typedef __attribute__((ext_vector_type(8))) short short8;
typedef __attribute__((ext_vector_type(4))) float floatx4;

// int-bridge casts (generic->AS1/AS3): LDS generic addr low 32 bits = LDS offset
#define AS1(p) ((const __attribute__((address_space(1))) void*)(uintptr_t)(p))
#define AS3(p) ((__attribute__((address_space(3))) void*)(unsigned int)(uintptr_t)(p))

__device__ __forceinline__ unsigned short f2bf(float f) {
    union { float f; unsigned int u; } v; v.f = f;
    unsigned int u = v.u;
    unsigned int r = (u + 0x7FFFu + ((u >> 16) & 1u)) >> 16;
    return (unsigned short)r;
}

__device__ __forceinline__ int pk_bf16(float a, float b) {
#if __has_builtin(__builtin_amdgcn_cvt_pk_bf16_f32)
    auto r = __builtin_amdgcn_cvt_pk_bf16_f32(a, b);
    int out; __builtin_memcpy(&out, &r, sizeof(int)); return out;
#else
    return (int)f2bf(a) | ((int)f2bf(b) << 16);
#endif
}

// ---------------- convert x (fp32 -> bf16), 4 elems/thread ----------------
__global__ __launch_bounds__(256) void cvt_x(const float* __restrict__ src,
                                             unsigned short* __restrict__ dst, int n4) {
    int i = blockIdx.x * blockDim.x + threadIdx.x;
    if (i < n4) {
        float4 v = ((const float4*)src)[i];
        int2 o = {pk_bf16(v.x, v.y), pk_bf16(v.z, v.w)};
        ((int2*)dst)[i] = o;
    }
}

// ------------- transpose + convert: src[R][C] fp32 -> dst[C][R] bf16 -------------
__global__ __launch_bounds__(256) void transpose_bf16(const float* __restrict__ src,
                                                      unsigned short* __restrict__ dst,
                                                      int R, int C) {
    __shared__ float tile[32][33];
    int c0 = blockIdx.x * 32, r0 = blockIdx.y * 32;
    int tc = threadIdx.x & 31, tr = (threadIdx.x >> 5) * 4;
#pragma unroll
    for (int i = 0; i < 4; ++i)
        tile[tr + i][tc] = src[(size_t)(r0 + tr + i) * C + c0 + tc];
    __syncthreads();
#pragma unroll
    for (int i = 0; i < 4; ++i)
        dst[(size_t)(c0 + tr + i) * R + r0 + tc] = f2bf(tile[tc][tr + i]);
}

// ---------------- 256x256 8-phase bf16 MFMA GEMM (m201-template port) ----------------
// C[M][N] = A[M][K] * Bt[N][K]^T.  8 waves (2M x 4N), per-wave 128x64 output.
// BK=64, 2-buf double buffer; each buffer = 2 half-tiles (128x64) of A and of B.
// Per K-tile: 4 phases.  Phase = { 4-8 ds_read_b128 (MFMA-consumed read LAST,
// so per-wave in-order lgkm drain covers the whole batch before the post-MFMA
// barrier) ; stage 1 half-tile (2 global_load_lds x16B) ; s_barrier ;
// compiler-counted lgkmcnt ; setprio(1) ; 16 MFMA ; setprio(0) ; s_barrier }.
//   ph0: read a(ks0),b(ks0)      stage A-h0(t+1)   mfma acc[0..3][*] ks0
//   ph1: read b(ks1),a47(ks0)    stage A-h1(t+1)   mfma acc[4..7][*] ks0
//   ph2: read a03(ks1)           stage B-h0(t+2)   mfma acc[0..3][*] ks1
//   ph3: read a47(ks1)           stage B-h1(t+2)   mfma acc[4..7][*] ks1
// Boundary: vmcnt(4) (only t+2's B stays in flight -- never drains to 0
// mid-loop), then one barrier.  WAR safety: a half-tile is re-staged >=1 full
// phase after its last read batch drained (checked per-phase above).
// LDS chunk swizzle (both-sides, rule 21): 16B chunk at (row, pos) holds global
// chunk pos ^ (row&7); frag reads spread 16 lanes over all 8 bank-groups.
// XCD-aware bijective block swizzle (gridDim.x % 8 == 0).
// Requires M%256==0, N%256==0, K%64==0.
template <bool OUT_BF16>
__global__ __launch_bounds__(512, 2) void gemm_bt256(const unsigned short* __restrict__ A,
                                                     const unsigned short* __restrict__ Bt,
                                                     void* __restrict__ Cout,
                                                     int M, int N, int K, int nbx) {
    __shared__ unsigned short Ah[2][2][128 * 64];   // [buf][half][row*64 + swz-chunk]
    __shared__ unsigned short Bh[2][2][128 * 64];

    const int tid = threadIdx.x;
    const int wave = tid >> 6, lane = tid & 63, quad = lane >> 4, l15 = lane & 15;
    const int wm = wave >> 2, wn = wave & 3;

    // XCD-aware bijective swizzle: launch id i -> XCD i%8 gets contiguous tiles.
    const int nwg = (int)gridDim.x;
    const int q8 = nwg >> 3;
    const int wgid = (int)blockIdx.x;
    const int swz = (wgid & 7) * q8 + (wgid >> 3);
    const int bm = (swz / nbx) * 256;
    const int bn = (swz % nbx) * 256;

    floatx4 acc[8][4];
    const floatx4 z = {0.f, 0.f, 0.f, 0.f};
#pragma unroll
    for (int mi = 0; mi < 8; ++mi)
#pragma unroll
        for (int ni = 0; ni < 4; ++ni) acc[mi][ni] = z;

    // Staging: half-tile = 128 rows x 64 K = 1024 16B-chunks; thread owns chunks
    // tid (rows 0-63) and tid+512 (rows 64-127), same swizzled col for both.
    const int r0 = tid >> 3;
    const int cc = ((tid & 7) ^ ((tid >> 3) & 7)) * 8;   // pre-swizzled source col
    const unsigned short* Asrc = A + (size_t)(bm + r0) * K + cc;
    const unsigned short* Bsrc = Bt + (size_t)(bn + r0) * K + cc;

    const int NT = K >> 6;

    auto stageA = [&](int t, int h) {
        const unsigned short* s0 = Asrc + (size_t)h * 128 * K + t * 64;
        unsigned short* d = &Ah[t & 1][h][tid * 8];
        __builtin_amdgcn_global_load_lds(AS1(s0), AS3(d), 16, 0, 0);
        __builtin_amdgcn_global_load_lds(AS1(s0 + (size_t)64 * K), AS3(d + 512 * 8), 16, 0, 0);
    };
    auto stageB = [&](int t, int h) {
        const unsigned short* s0 = Bsrc + (size_t)h * 128 * K + t * 64;
        unsigned short* d = &Bh[t & 1][h][tid * 8];
        __builtin_amdgcn_global_load_lds(AS1(s0), AS3(d), 16, 0, 0);
        __builtin_amdgcn_global_load_lds(AS1(s0 + (size_t)64 * K), AS3(d + 512 * 8), 16, 0, 0);
    };

    // Fragment-read addressing: global chunk c = ks*4 + quad stored at
    // pos = c ^ (row&7); row&7 == l15&7 for all frag rows (multiples of 16/64).
    const int kc0 = ((quad     ) ^ (l15 & 7)) * 8;
    const int kc1 = ((quad ^ 4) ^ (l15 & 7)) * 8;
    const int brb = (wn & 1) * 64;   // row base inside B half (wn>>1)

    // ---- prologue: A(0),B(0),B(1) staged; wait A(0)+B(0) (B(1) stays in flight) ----
    stageA(0, 0); stageA(0, 1);
    stageB(0, 0); stageB(0, 1);
    if (NT > 1) {
        stageB(1, 0); stageB(1, 1);
        asm volatile("s_waitcnt vmcnt(4)" ::: "memory");
    } else {
        asm volatile("s_waitcnt vmcnt(0)" ::: "memory");
    }
    __builtin_amdgcn_s_barrier();

    for (int t = 0; t < NT; ++t) {
        const int s = t & 1;
        const unsigned short* Ap = &Ah[s][wm][0];
        const unsigned short* Bp = &Bh[s][wn >> 1][0];
        short8 a0[4], a1[4], b0[4], b1[4];

        // ---- phase 0 ----
#pragma unroll
        for (int mi = 0; mi < 4; ++mi)
            a0[mi] = *(const short8*)&Ap[(mi * 16 + l15) * 64 + kc0];
#pragma unroll
        for (int ni = 0; ni < 4; ++ni)
            b0[ni] = *(const short8*)&Bp[(brb + ni * 16 + l15) * 64 + kc0];
        if (t + 1 < NT) stageA(t + 1, 0);
        __builtin_amdgcn_s_barrier();
        __builtin_amdgcn_s_setprio(1);
#pragma unroll
        for (int mi = 0; mi < 4; ++mi)
#pragma unroll
            for (int ni = 0; ni < 4; ++ni)
                acc[mi][ni] = __builtin_amdgcn_mfma_f32_16x16x32_bf16(b0[ni], a0[mi], acc[mi][ni], 0, 0, 0);
        __builtin_amdgcn_s_setprio(0);
        __builtin_amdgcn_s_barrier();

        // ---- phase 1 (b1 issued BEFORE a1: a1 is MFMA-consumed last -> b1 drained) ----
#pragma unroll
        for (int ni = 0; ni < 4; ++ni)
            b1[ni] = *(const short8*)&Bp[(brb + ni * 16 + l15) * 64 + kc1];
#pragma unroll
        for (int mi = 0; mi < 4; ++mi)
            a1[mi] = *(const short8*)&Ap[(64 + mi * 16 + l15) * 64 + kc0];
        if (t + 1 < NT) stageA(t + 1, 1);
        __builtin_amdgcn_s_barrier();
        __builtin_amdgcn_s_setprio(1);
#pragma unroll
        for (int mi = 0; mi < 4; ++mi)
#pragma unroll
            for (int ni = 0; ni < 4; ++ni)
                acc[4 + mi][ni] = __builtin_amdgcn_mfma_f32_16x16x32_bf16(b0[ni], a1[mi], acc[4 + mi][ni], 0, 0, 0);
        __builtin_amdgcn_s_setprio(0);
        __builtin_amdgcn_s_barrier();

        // ---- phase 2 (B halves of this buf fully drained -> safe to re-stage) ----
#pragma unroll
        for (int mi = 0; mi < 4; ++mi)
            a0[mi] = *(const short8*)&Ap[(mi * 16 + l15) * 64 + kc1];
        if (t + 2 < NT) stageB(t + 2, 0);
        __builtin_amdgcn_s_barrier();
        __builtin_amdgcn_s_setprio(1);
#pragma unroll
        for (int mi = 0; mi < 4; ++mi)
#pragma unroll
            for (int ni = 0; ni < 4; ++ni)
                acc[mi][ni] = __builtin_amdgcn_mfma_f32_16x16x32_bf16(b1[ni], a0[mi], acc[mi][ni], 0, 0, 0);
        __builtin_amdgcn_s_setprio(0);
        __builtin_amdgcn_s_barrier();

        // ---- phase 3 ----
#pragma unroll
        for (int mi = 0; mi < 4; ++mi)
            a1[mi] = *(const short8*)&Ap[(64 + mi * 16 + l15) * 64 + kc1];
        if (t + 2 < NT) stageB(t + 2, 1);
        __builtin_amdgcn_s_barrier();
        __builtin_amdgcn_s_setprio(1);
#pragma unroll
        for (int mi = 0; mi < 4; ++mi)
#pragma unroll
            for (int ni = 0; ni < 4; ++ni)
                acc[4 + mi][ni] = __builtin_amdgcn_mfma_f32_16x16x32_bf16(b1[ni], a1[mi], acc[4 + mi][ni], 0, 0, 0);
        __builtin_amdgcn_s_setprio(0);

        // ---- K-tile boundary: A(t+1)+B(t+1) resident; only B(t+2) in flight ----
        if (t + 2 < NT)      asm volatile("s_waitcnt vmcnt(4)" ::: "memory");
        else if (t + 1 < NT) asm volatile("s_waitcnt vmcnt(0)" ::: "memory");
        if (t + 1 < NT) __builtin_amdgcn_s_barrier();
    }

    // ---- epilogue: C^T fragment layout (row from A-frag, col = ni*16+quad*4+r) ----
#pragma unroll
    for (int mi = 0; mi < 8; ++mi) {
        const size_t row = (size_t)(bm + wm * 128 + mi * 16 + l15);
#pragma unroll
        for (int ni = 0; ni < 4; ++ni) {
            const size_t col = (size_t)(bn + wn * 64 + ni * 16 + quad * 4);
            if (OUT_BF16) {
                int2 val = {pk_bf16(acc[mi][ni][0], acc[mi][ni][1]),
                            pk_bf16(acc[mi][ni][2], acc[mi][ni][3])};
                *(int2*)((unsigned short*)Cout + row * N + col) = val;
            } else {
                *(float4*)((float*)Cout + row * N + col) = *(const float4*)&acc[mi][ni];
            }
        }
    }
}

// ---------------- sliding-window flash attention (S^T, 32q/wave) ----------------
// Grid (32 q-blocks of 128, 64 b*h). Block: 4 waves; wave w owns 32 queries.
// Wave-pair p = w>>1 active in chunks [p, p+4] of 6 (83% busy).
// S^T = K.Q^T; softmax stats per-lane (q=l15); P->A-frag via ds_bpermute.
// K/V double-buffered (stride 72: 2-way bank alias = free), reg-prefetched.
__global__ __launch_bounds__(256, 3) void attn_swin(const unsigned short* __restrict__ qkv,
                                                    unsigned short* __restrict__ attn_out) {
    __shared__ unsigned short Klds[2][64 * 72];
    __shared__ unsigned short Vtl[2][64 * 72];

    const int blk = blockIdx.x, bh = blockIdx.y;
    const int b = bh >> 4, h = bh & 15;
    const int tid = threadIdx.x;
    const int wave = tid >> 6, lane = tid & 63, quad = lane >> 4, l15 = lane & 15;
    const int pair = wave >> 1;            // diagonal band of the wave-pair
    const int qoff = (wave & 1) * 32;      // offset within the pair's 64-q band
    const int qi_base = blk * 128 + wave * 32;
    const size_t seqbase = (size_t)b * 4096;

    // Q fragments hoisted once (A-layout == B-layout of Q^T)
    short8 qf[2][2];
#pragma unroll
    for (int qt = 0; qt < 2; ++qt)
#pragma unroll
        for (int ks = 0; ks < 2; ++ks)
            qf[qt][ks] = *(const short8*)(qkv + (seqbase + qi_base + qt * 16 + l15) * 3072
                                          + h * 64 + ks * 32 + quad * 8);

    floatx4 o[2][4];  // [qt][dt]: lane holds O[q=qt*16+l15][d=dt*16+quad*4+r]
    const floatx4 z = {0.f, 0.f, 0.f, 0.f};
    float m_run[2], l_run[2];
#pragma unroll
    for (int qt = 0; qt < 2; ++qt) {
#pragma unroll
        for (int dt = 0; dt < 4; ++dt) o[qt][dt] = z;
        m_run[qt] = -1.0e30f; l_run[qt] = 0.f;
    }

    const int kwin0 = blk * 128 - 256;
    const int c0 = (blk >= 2) ? 0 : (4 - 2 * blk);
    const int cLo = pair, cHi = pair + 4;
    const int sk_key = tid >> 2, sk_g = (tid & 3) * 16;
    const int sv_key = tid & 63, sv_dg = (tid >> 6) * 16;
    const float SC = 0.18033688f;  // dh^-0.5 * log2(e)

    // bpermute lane addressing: src lane = (quad&1)*32 + (t>>1)*16 + l15
    const int addrA = (((quad & 1) << 5) + l15) << 2;
    const int addrB = addrA + 64;
    const bool hiq = quad >= 2;

    int4 kvreg[4];
    auto load_kv = [&](int k0) {
        const int4* sk = (const int4*)(qkv + (seqbase + k0 + sk_key) * 3072 + 1024 + h * 64 + sk_g);
        kvreg[0] = sk[0]; kvreg[1] = sk[1];
        const int4* sv = (const int4*)(qkv + (seqbase + k0 + sv_key) * 3072 + 2048 + h * 64 + sv_dg);
        kvreg[2] = sv[0]; kvreg[3] = sv[1];
    };
    auto write_kv = [&](int buf) {
        *(int4*)&Klds[buf][sk_key * 72 + sk_g]     = kvreg[0];
        *(int4*)&Klds[buf][sk_key * 72 + sk_g + 8] = kvreg[1];
        union { unsigned short s[16]; int4 q[2]; } t;
        t.q[0] = kvreg[2]; t.q[1] = kvreg[3];
#pragma unroll
        for (int i = 0; i < 16; ++i) Vtl[buf][(sv_dg + i) * 72 + sv_key] = t.s[i];
    };

    load_kv(kwin0 + c0 * 64);   // == key 0 for clipped blocks
    write_kv(0);

    for (int c = c0; c < 6; ++c) {
        const int buf = (c - c0) & 1;
        __syncthreads();
        if (c < 5) load_kv(kwin0 + (c + 1) * 64);  // prefetch overlaps compute

        if (c >= cLo && c <= cHi) {
#pragma unroll
            for (int qt = 0; qt < 2; ++qt) {
                // ---- S^T = K.Q^T (kf transient per qt to cap VGPR) ----
                floatx4 sT[4];
#pragma unroll
                for (int ni = 0; ni < 4; ++ni) sT[ni] = z;
#pragma unroll
                for (int ks = 0; ks < 2; ++ks) {
#pragma unroll
                    for (int ni = 0; ni < 4; ++ni) {
                        short8 kf = *(const short8*)&Klds[buf][(ni * 16 + l15) * 72 + ks * 32 + quad * 8];
                        sT[ni] = __builtin_amdgcn_mfma_f32_16x16x32_bf16(kf, qf[qt][ks], sT[ni], 0, 0, 0);
                    }
                }

                // ---- V^T fragments early (latency hidden under softmax VALU) ----
                short8 vf[4][2];
#pragma unroll
                for (int dt = 0; dt < 4; ++dt)
#pragma unroll
                    for (int ks = 0; ks < 2; ++ks)
                        vf[dt][ks] = *(const short8*)&Vtl[buf][(dt * 16 + l15) * 72 + ks * 32 + quad * 8];

                // ---- mask diagonal chunks (key j = ni*16+quad*4+r, query i64) ----
                const int i64 = qoff + qt * 16 + l15;
                if (c == cLo) {            // valid iff j >= i64+1
#pragma unroll
                    for (int ni = 0; ni < 4; ++ni) {
                        int jb = ni * 16 + quad * 4;
#pragma unroll
                        for (int r = 0; r < 4; ++r)
                            if (jb + r < i64 + 1) sT[ni][r] = -3.0e38f;
                    }
                } else if (c == cHi) {     // valid iff j <= i64
#pragma unroll
                    for (int ni = 0; ni < 4; ++ni) {
                        int jb = ni * 16 + quad * 4;
#pragma unroll
                        for (int r = 0; r < 4; ++r)
                            if (jb + r > i64) sT[ni][r] = -3.0e38f;
                    }
                }

                // ---- online softmax (log2 domain, per-lane stats) ----
                float mx = -3.0e38f;
#pragma unroll
                for (int ni = 0; ni < 4; ++ni)
#pragma unroll
                    for (int r = 0; r < 4; ++r) mx = fmaxf(mx, sT[ni][r]);
                mx = fmaxf(mx, __shfl_xor(mx, 16));
                mx = fmaxf(mx, __shfl_xor(mx, 32));
                float mn = fmaxf(m_run[qt], mx * SC);
                float alpha = __builtin_amdgcn_exp2f(m_run[qt] - mn);
                m_run[qt] = mn;

                float ls = 0.f;
                int Pk[4][2];
#pragma unroll
                for (int ni = 0; ni < 4; ++ni) {
                    float p0 = __builtin_amdgcn_exp2f(fmaf(sT[ni][0], SC, -mn));
                    float p1 = __builtin_amdgcn_exp2f(fmaf(sT[ni][1], SC, -mn));
                    float p2 = __builtin_amdgcn_exp2f(fmaf(sT[ni][2], SC, -mn));
                    float p3 = __builtin_amdgcn_exp2f(fmaf(sT[ni][3], SC, -mn));
                    ls += (p0 + p1) + (p2 + p3);
                    Pk[ni][0] = pk_bf16(p0, p1);
                    Pk[ni][1] = pk_bf16(p2, p3);
                }
                ls += __shfl_xor(ls, 16);
                ls += __shfl_xor(ls, 32);
                l_run[qt] = l_run[qt] * alpha + ls;
#pragma unroll
                for (int dt = 0; dt < 4; ++dt)
#pragma unroll
                    for (int r = 0; r < 4; ++r) o[qt][dt][r] *= alpha;

                // ---- quad-permute P (C-layout) -> A-frag, then PV ----
#pragma unroll
                for (int ks = 0; ks < 2; ++ks) {
                    int a0 = __builtin_amdgcn_ds_bpermute(addrA, Pk[2 * ks][0]);
                    int b0 = __builtin_amdgcn_ds_bpermute(addrA, Pk[2 * ks + 1][0]);
                    int a1 = __builtin_amdgcn_ds_bpermute(addrA, Pk[2 * ks][1]);
                    int b1 = __builtin_amdgcn_ds_bpermute(addrA, Pk[2 * ks + 1][1]);
                    int a2 = __builtin_amdgcn_ds_bpermute(addrB, Pk[2 * ks][0]);
                    int b2 = __builtin_amdgcn_ds_bpermute(addrB, Pk[2 * ks + 1][0]);
                    int a3 = __builtin_amdgcn_ds_bpermute(addrB, Pk[2 * ks][1]);
                    int b3 = __builtin_amdgcn_ds_bpermute(addrB, Pk[2 * ks + 1][1]);
                    union { int i[4]; short8 v; } u;
                    u.i[0] = hiq ? b0 : a0;
                    u.i[1] = hiq ? b1 : a1;
                    u.i[2] = hiq ? b2 : a2;
                    u.i[3] = hiq ? b3 : a3;
#pragma unroll
                    for (int dt = 0; dt < 4; ++dt)
                        o[qt][dt] = __builtin_amdgcn_mfma_f32_16x16x32_bf16(vf[dt][ks], u.v, o[qt][dt], 0, 0, 0);
                }
            }
        }

        if (c < 5) write_kv(buf ^ 1);
    }

    // ---- epilogue ----
#pragma unroll
    for (int qt = 0; qt < 2; ++qt) {
        float rl = __builtin_amdgcn_rcpf(l_run[qt]);
        size_t rowb = (seqbase + qi_base + qt * 16 + l15) * 1024 + h * 64;
#pragma unroll
        for (int dt = 0; dt < 4; ++dt) {
            int2 val = {pk_bf16(o[qt][dt][0] * rl, o[qt][dt][1] * rl),
                        pk_bf16(o[qt][dt][2] * rl, o[qt][dt][3] * rl)};
            *(int2*)(attn_out + rowb + dt * 16 + quad * 4) = val;
        }
    }
}

extern "C" void kernel_launch(void* const* d_in, const int* in_sizes, int n_in,
                              void* d_out, int out_size, void* d_ws, size_t ws_size,
                              hipStream_t stream) {
    const float* x     = (const float*)d_in[0];  // [4,4096,1024]
    const float* w_qkv = (const float*)d_in[1];  // [1024,3072]
    const float* w_out = (const float*)d_in[2];  // [1024,1024]
    float* out = (float*)d_out;                  // [4,4096,1024]

    unsigned short* xb    = (unsigned short*)d_ws;                 // 16384*1024
    unsigned short* wqkvT = xb    + (size_t)16384 * 1024;          // 3072*1024
    unsigned short* woutT = wqkvT + (size_t)3072 * 1024;           // 1024*1024
    unsigned short* qkv   = woutT + (size_t)1024 * 1024;           // 16384*3072
    unsigned short* attn  = qkv   + (size_t)16384 * 3072;          // 16384*1024

    cvt_x<<<16384, 256, 0, stream>>>(x, xb, 4194304);
    transpose_bf16<<<dim3(96, 32), 256, 0, stream>>>(w_qkv, wqkvT, 1024, 3072);
    transpose_bf16<<<dim3(32, 32), 256, 0, stream>>>(w_out, woutT, 1024, 1024);
    // QKV: M=16384, N=3072 -> 64x12 = 768 tiles (768 % 8 == 0)
    gemm_bt256<true><<<768, 512, 0, stream>>>(xb, wqkvT, qkv, 16384, 3072, 1024, 12);
    attn_swin<<<dim3(32, 64), 256, 0, stream>>>(qkv, attn);
    // out-proj: M=16384, N=1024 -> 64x4 = 256 tiles (256 % 8 == 0)
    gemm_bt256<false><<<256, 512, 0, stream>>>(attn, woutT, out, 16384, 1024, 1024, 4);
}

// Round 4
// 354.934 us; speedup vs baseline: 1.1706x; 1.0170x over previous
//
#include <hip/hip_runtime.h>

typedef __attribute__((ext_vector_type(8))) short short8;
typedef __attribute__((ext_vector_type(4))) float floatx4;

// int-bridge casts (generic->AS1/AS3): LDS generic addr low 32 bits = LDS offset
#define AS1(p) ((const __attribute__((address_space(1))) void*)(uintptr_t)(p))
#define AS3(p) ((__attribute__((address_space(3))) void*)(unsigned int)(uintptr_t)(p))

__device__ __forceinline__ unsigned short f2bf(float f) {
    union { float f; unsigned int u; } v; v.f = f;
    unsigned int u = v.u;
    unsigned int r = (u + 0x7FFFu + ((u >> 16) & 1u)) >> 16;
    return (unsigned short)r;
}

__device__ __forceinline__ int pk_bf16(float a, float b) {
#if __has_builtin(__builtin_amdgcn_cvt_pk_bf16_f32)
    auto r = __builtin_amdgcn_cvt_pk_bf16_f32(a, b);
    int out; __builtin_memcpy(&out, &r, sizeof(int)); return out;
#else
    return (int)f2bf(a) | ((int)f2bf(b) << 16);
#endif
}

// ---------------- convert x (fp32 -> bf16), 4 elems/thread ----------------
__global__ __launch_bounds__(256) void cvt_x(const float* __restrict__ src,
                                             unsigned short* __restrict__ dst, int n4) {
    int i = blockIdx.x * blockDim.x + threadIdx.x;
    if (i < n4) {
        float4 v = ((const float4*)src)[i];
        int2 o = {pk_bf16(v.x, v.y), pk_bf16(v.z, v.w)};
        ((int2*)dst)[i] = o;
    }
}

// ------------- transpose + convert: src[R][C] fp32 -> dst[C][R] bf16 -------------
__global__ __launch_bounds__(256) void transpose_bf16(const float* __restrict__ src,
                                                      unsigned short* __restrict__ dst,
                                                      int R, int C) {
    __shared__ float tile[32][33];
    int c0 = blockIdx.x * 32, r0 = blockIdx.y * 32;
    int tc = threadIdx.x & 31, tr = (threadIdx.x >> 5) * 4;
#pragma unroll
    for (int i = 0; i < 4; ++i)
        tile[tr + i][tc] = src[(size_t)(r0 + tr + i) * C + c0 + tc];
    __syncthreads();
#pragma unroll
    for (int i = 0; i < 4; ++i)
        dst[(size_t)(c0 + tr + i) * R + r0 + tc] = f2bf(tile[tc][tr + i]);
}

// -------------- 128x256-tile multi-block-per-CU bf16 MFMA GEMM --------------
// C[M][N] = A[M][K] * Bt[N][K]^T.  4 waves (1M x 4N), per-wave 128x64 output
// (reads/MFMA = 0.375, same as 256^2/8-wave).  BK=32, 2-slot LDS double buffer,
// 48 KiB/block -> 2-3 blocks resident per CU.  KEY IDEA (m114 inter-block
// overlap): rounds 1-3 proved that with ONE barrier-locked block per CU the
// LDS fragment-read drain and the MFMA pipe serialize (all waves' round-robin
// reads finish together -> no wave skew).  Independent blocks have independent
// barrier groups -> while block A drains ds_reads, block B's MFMAs own the
// matrix pipe.  Per tile: stage(t+1) first (VMEM latency hides under the whole
// tile), 12 ds_read_b128 (a1 issued before MFMA-c1 so it drains under it),
// 2x16 MFMA, per-wave vmcnt(0) (cheap: loads issued a full tile ago), ONE raw
// s_barrier.  WAR: stage into slot s^1 at top of t is ordered after the end-of-
// (t-1) barrier, which followed all reads of s^1 (each consumed by MFMA before
// that barrier).  RAW: reads of t+1 follow the barrier that followed every
// wave's own vmcnt(0).  LDS chunk swizzle (both sides, rule 21): 16B chunk at
// (row,pos) holds global chunk pos ^ ((row>>1)&3) -> frag reads 2-way max
// (free, m136).  XCD-aware bijective block swizzle (gridDim.x % 8 == 0).
// Requires M%128==0, N%256==0, K%32==0.
template <bool OUT_BF16>
__global__ __launch_bounds__(256, 2) void gemm_bt128(const unsigned short* __restrict__ A,
                                                     const unsigned short* __restrict__ Bt,
                                                     void* __restrict__ Cout,
                                                     int M, int N, int K, int nbx) {
    __shared__ unsigned short Asm[2][128 * 32];
    __shared__ unsigned short Bsm[2][256 * 32];

    const int tid = threadIdx.x;
    const int wn = tid >> 6, lane = tid & 63, quad = lane >> 4, l15 = lane & 15;

    // XCD-aware bijective swizzle: launch id i -> XCD i%8 gets contiguous tiles.
    const int nwg = (int)gridDim.x;
    const int q8 = nwg >> 3;
    const int wgid = (int)blockIdx.x;
    const int swz = (wgid & 7) * q8 + (wgid >> 3);
    const int bm = (swz / nbx) * 128;
    const int bn = (swz % nbx) * 256;

    floatx4 acc[8][4];
    const floatx4 z = {0.f, 0.f, 0.f, 0.f};
#pragma unroll
    for (int mi = 0; mi < 8; ++mi)
#pragma unroll
        for (int ni = 0; ni < 4; ++ni) acc[mi][ni] = z;

    // Staging.  A tile = 128x32 = 512 16B-chunks (thread owns tid, tid+256);
    // B tile = 256x32 = 1024 chunks (tid, +256, +512, +768).  Chunk d sits at
    // LDS offset d*16B (linear, gload_lds-legal) and holds global
    // (row = d>>2, colchunk = (d&3) ^ ((d>>3)&3)).
    const int dA0 = tid, dA1 = tid + 256;
    const int rA0 = dA0 >> 2, cA0 = ((dA0 & 3) ^ ((dA0 >> 3) & 3)) * 8;
    const int rA1 = dA1 >> 2, cA1 = ((dA1 & 3) ^ ((dA1 >> 3) & 3)) * 8;
    const unsigned short* Asrc0 = A + (size_t)(bm + rA0) * K + cA0;
    const unsigned short* Asrc1 = A + (size_t)(bm + rA1) * K + cA1;
    const unsigned short* Bsrc[4];
    int dB[4];
#pragma unroll
    for (int j = 0; j < 4; ++j) {
        dB[j] = tid + j * 256;
        const int r = dB[j] >> 2, c = ((dB[j] & 3) ^ ((dB[j] >> 3) & 3)) * 8;
        Bsrc[j] = Bt + (size_t)(bn + r) * K + c;
    }

    const int NT = K >> 5;

    auto stage = [&](int t) {
        const int s = t & 1, ko = t * 32;
        __builtin_amdgcn_global_load_lds(AS1(Asrc0 + ko), AS3(&Asm[s][dA0 * 8]), 16, 0, 0);
        __builtin_amdgcn_global_load_lds(AS1(Asrc1 + ko), AS3(&Asm[s][dA1 * 8]), 16, 0, 0);
#pragma unroll
        for (int j = 0; j < 4; ++j)
            __builtin_amdgcn_global_load_lds(AS1(Bsrc[j] + ko), AS3(&Bsm[s][dB[j] * 8]), 16, 0, 0);
    };

    // Fragment-read addressing: frag rows are (16-multiple + l15), so
    // (row>>1)&3 == (l15>>1)&3 -> swizzled chunk is frag-index-independent.
    const int qc = (quad ^ ((l15 >> 1) & 3)) * 8;
    const int brow = wn * 64 + l15;

    // ---- prologue ----
    stage(0);
    asm volatile("s_waitcnt vmcnt(0)" ::: "memory");
    __builtin_amdgcn_s_barrier();

    for (int t = 0; t < NT; ++t) {
        const int s = t & 1;
        const unsigned short* Ap = Asm[s];
        const unsigned short* Bp = Bsm[s];
        if (t + 1 < NT) stage(t + 1);

        short8 b[4], a0[4], a1[4];
#pragma unroll
        for (int ni = 0; ni < 4; ++ni)
            b[ni] = *(const short8*)&Bp[(brow + ni * 16) * 32 + qc];
#pragma unroll
        for (int mi = 0; mi < 4; ++mi)
            a0[mi] = *(const short8*)&Ap[(mi * 16 + l15) * 32 + qc];
#pragma unroll
        for (int mi = 0; mi < 4; ++mi)
            a1[mi] = *(const short8*)&Ap[(64 + mi * 16 + l15) * 32 + qc];

        // MFMA c1 consumes b+a0 (counted lgkm leaves a1 draining under it)
        __builtin_amdgcn_s_setprio(1);
#pragma unroll
        for (int mi = 0; mi < 4; ++mi)
#pragma unroll
            for (int ni = 0; ni < 4; ++ni)
                acc[mi][ni] = __builtin_amdgcn_mfma_f32_16x16x32_bf16(b[ni], a0[mi], acc[mi][ni], 0, 0, 0);
#pragma unroll
        for (int mi = 0; mi < 4; ++mi)
#pragma unroll
            for (int ni = 0; ni < 4; ++ni)
                acc[4 + mi][ni] = __builtin_amdgcn_mfma_f32_16x16x32_bf16(b[ni], a1[mi], acc[4 + mi][ni], 0, 0, 0);
        __builtin_amdgcn_s_setprio(0);

        // tile t+1 resident (per-wave; issued a full tile ago) then sync
        asm volatile("s_waitcnt vmcnt(0)" ::: "memory");
        __builtin_amdgcn_s_barrier();
    }

    // ---- epilogue: C^T fragment layout (row from A-frag, col = ni*16+quad*4+r) ----
#pragma unroll
    for (int mi = 0; mi < 8; ++mi) {
        const size_t row = (size_t)(bm + mi * 16 + l15);
#pragma unroll
        for (int ni = 0; ni < 4; ++ni) {
            const size_t col = (size_t)(bn + wn * 64 + ni * 16 + quad * 4);
            if (OUT_BF16) {
                int2 val = {pk_bf16(acc[mi][ni][0], acc[mi][ni][1]),
                            pk_bf16(acc[mi][ni][2], acc[mi][ni][3])};
                *(int2*)((unsigned short*)Cout + row * N + col) = val;
            } else {
                *(float4*)((float*)Cout + row * N + col) = *(const float4*)&acc[mi][ni];
            }
        }
    }
}

// ---------------- sliding-window flash attention (S^T, 32q/wave) ----------------
// Grid (32 q-blocks of 128, 64 b*h). Block: 4 waves; wave w owns 32 queries.
// Wave-pair p = w>>1 active in chunks [p, p+4] of 6 (83% busy).
// S^T = K.Q^T; softmax stats per-lane (q=l15); P->A-frag via ds_bpermute.
// K/V double-buffered (stride 72: 2-way bank alias = free), reg-prefetched.
__global__ __launch_bounds__(256, 3) void attn_swin(const unsigned short* __restrict__ qkv,
                                                    unsigned short* __restrict__ attn_out) {
    __shared__ unsigned short Klds[2][64 * 72];
    __shared__ unsigned short Vtl[2][64 * 72];

    const int blk = blockIdx.x, bh = blockIdx.y;
    const int b = bh >> 4, h = bh & 15;
    const int tid = threadIdx.x;
    const int wave = tid >> 6, lane = tid & 63, quad = lane >> 4, l15 = lane & 15;
    const int pair = wave >> 1;            // diagonal band of the wave-pair
    const int qoff = (wave & 1) * 32;      // offset within the pair's 64-q band
    const int qi_base = blk * 128 + wave * 32;
    const size_t seqbase = (size_t)b * 4096;

    // Q fragments hoisted once (A-layout == B-layout of Q^T)
    short8 qf[2][2];
#pragma unroll
    for (int qt = 0; qt < 2; ++qt)
#pragma unroll
        for (int ks = 0; ks < 2; ++ks)
            qf[qt][ks] = *(const short8*)(qkv + (seqbase + qi_base + qt * 16 + l15) * 3072
                                          + h * 64 + ks * 32 + quad * 8);

    floatx4 o[2][4];  // [qt][dt]: lane holds O[q=qt*16+l15][d=dt*16+quad*4+r]
    const floatx4 z = {0.f, 0.f, 0.f, 0.f};
    float m_run[2], l_run[2];
#pragma unroll
    for (int qt = 0; qt < 2; ++qt) {
#pragma unroll
        for (int dt = 0; dt < 4; ++dt) o[qt][dt] = z;
        m_run[qt] = -1.0e30f; l_run[qt] = 0.f;
    }

    const int kwin0 = blk * 128 - 256;
    const int c0 = (blk >= 2) ? 0 : (4 - 2 * blk);
    const int cLo = pair, cHi = pair + 4;
    const int sk_key = tid >> 2, sk_g = (tid & 3) * 16;
    const int sv_key = tid & 63, sv_dg = (tid >> 6) * 16;
    const float SC = 0.18033688f;  // dh^-0.5 * log2(e)

    // bpermute lane addressing: src lane = (quad&1)*32 + (t>>1)*16 + l15
    const int addrA = (((quad & 1) << 5) + l15) << 2;
    const int addrB = addrA + 64;
    const bool hiq = quad >= 2;

    int4 kvreg[4];
    auto load_kv = [&](int k0) {
        const int4* sk = (const int4*)(qkv + (seqbase + k0 + sk_key) * 3072 + 1024 + h * 64 + sk_g);
        kvreg[0] = sk[0]; kvreg[1] = sk[1];
        const int4* sv = (const int4*)(qkv + (seqbase + k0 + sv_key) * 3072 + 2048 + h * 64 + sv_dg);
        kvreg[2] = sv[0]; kvreg[3] = sv[1];
    };
    auto write_kv = [&](int buf) {
        *(int4*)&Klds[buf][sk_key * 72 + sk_g]     = kvreg[0];
        *(int4*)&Klds[buf][sk_key * 72 + sk_g + 8] = kvreg[1];
        union { unsigned short s[16]; int4 q[2]; } t;
        t.q[0] = kvreg[2]; t.q[1] = kvreg[3];
#pragma unroll
        for (int i = 0; i < 16; ++i) Vtl[buf][(sv_dg + i) * 72 + sv_key] = t.s[i];
    };

    load_kv(kwin0 + c0 * 64);   // == key 0 for clipped blocks
    write_kv(0);

    for (int c = c0; c < 6; ++c) {
        const int buf = (c - c0) & 1;
        __syncthreads();
        if (c < 5) load_kv(kwin0 + (c + 1) * 64);  // prefetch overlaps compute

        if (c >= cLo && c <= cHi) {
#pragma unroll
            for (int qt = 0; qt < 2; ++qt) {
                // ---- S^T = K.Q^T (kf transient per qt to cap VGPR) ----
                floatx4 sT[4];
#pragma unroll
                for (int ni = 0; ni < 4; ++ni) sT[ni] = z;
#pragma unroll
                for (int ks = 0; ks < 2; ++ks) {
#pragma unroll
                    for (int ni = 0; ni < 4; ++ni) {
                        short8 kf = *(const short8*)&Klds[buf][(ni * 16 + l15) * 72 + ks * 32 + quad * 8];
                        sT[ni] = __builtin_amdgcn_mfma_f32_16x16x32_bf16(kf, qf[qt][ks], sT[ni], 0, 0, 0);
                    }
                }

                // ---- V^T fragments early (latency hidden under softmax VALU) ----
                short8 vf[4][2];
#pragma unroll
                for (int dt = 0; dt < 4; ++dt)
#pragma unroll
                    for (int ks = 0; ks < 2; ++ks)
                        vf[dt][ks] = *(const short8*)&Vtl[buf][(dt * 16 + l15) * 72 + ks * 32 + quad * 8];

                // ---- mask diagonal chunks (key j = ni*16+quad*4+r, query i64) ----
                const int i64 = qoff + qt * 16 + l15;
                if (c == cLo) {            // valid iff j >= i64+1
#pragma unroll
                    for (int ni = 0; ni < 4; ++ni) {
                        int jb = ni * 16 + quad * 4;
#pragma unroll
                        for (int r = 0; r < 4; ++r)
                            if (jb + r < i64 + 1) sT[ni][r] = -3.0e38f;
                    }
                } else if (c == cHi) {     // valid iff j <= i64
#pragma unroll
                    for (int ni = 0; ni < 4; ++ni) {
                        int jb = ni * 16 + quad * 4;
#pragma unroll
                        for (int r = 0; r < 4; ++r)
                            if (jb + r > i64) sT[ni][r] = -3.0e38f;
                    }
                }

                // ---- online softmax (log2 domain, per-lane stats) ----
                float mx = -3.0e38f;
#pragma unroll
                for (int ni = 0; ni < 4; ++ni)
#pragma unroll
                    for (int r = 0; r < 4; ++r) mx = fmaxf(mx, sT[ni][r]);
                mx = fmaxf(mx, __shfl_xor(mx, 16));
                mx = fmaxf(mx, __shfl_xor(mx, 32));
                float mn = fmaxf(m_run[qt], mx * SC);
                float alpha = __builtin_amdgcn_exp2f(m_run[qt] - mn);
                m_run[qt] = mn;

                float ls = 0.f;
                int Pk[4][2];
#pragma unroll
                for (int ni = 0; ni < 4; ++ni) {
                    float p0 = __builtin_amdgcn_exp2f(fmaf(sT[ni][0], SC, -mn));
                    float p1 = __builtin_amdgcn_exp2f(fmaf(sT[ni][1], SC, -mn));
                    float p2 = __builtin_amdgcn_exp2f(fmaf(sT[ni][2], SC, -mn));
                    float p3 = __builtin_amdgcn_exp2f(fmaf(sT[ni][3], SC, -mn));
                    ls += (p0 + p1) + (p2 + p3);
                    Pk[ni][0] = pk_bf16(p0, p1);
                    Pk[ni][1] = pk_bf16(p2, p3);
                }
                ls += __shfl_xor(ls, 16);
                ls += __shfl_xor(ls, 32);
                l_run[qt] = l_run[qt] * alpha + ls;
#pragma unroll
                for (int dt = 0; dt < 4; ++dt)
#pragma unroll
                    for (int r = 0; r < 4; ++r) o[qt][dt][r] *= alpha;

                // ---- quad-permute P (C-layout) -> A-frag, then PV ----
#pragma unroll
                for (int ks = 0; ks < 2; ++ks) {
                    int a0 = __builtin_amdgcn_ds_bpermute(addrA, Pk[2 * ks][0]);
                    int b0 = __builtin_amdgcn_ds_bpermute(addrA, Pk[2 * ks + 1][0]);
                    int a1 = __builtin_amdgcn_ds_bpermute(addrA, Pk[2 * ks][1]);
                    int b1 = __builtin_amdgcn_ds_bpermute(addrA, Pk[2 * ks + 1][1]);
                    int a2 = __builtin_amdgcn_ds_bpermute(addrB, Pk[2 * ks][0]);
                    int b2 = __builtin_amdgcn_ds_bpermute(addrB, Pk[2 * ks + 1][0]);
                    int a3 = __builtin_amdgcn_ds_bpermute(addrB, Pk[2 * ks][1]);
                    int b3 = __builtin_amdgcn_ds_bpermute(addrB, Pk[2 * ks + 1][1]);
                    union { int i[4]; short8 v; } u;
                    u.i[0] = hiq ? b0 : a0;
                    u.i[1] = hiq ? b1 : a1;
                    u.i[2] = hiq ? b2 : a2;
                    u.i[3] = hiq ? b3 : a3;
#pragma unroll
                    for (int dt = 0; dt < 4; ++dt)
                        o[qt][dt] = __builtin_amdgcn_mfma_f32_16x16x32_bf16(vf[dt][ks], u.v, o[qt][dt], 0, 0, 0);
                }
            }
        }

        if (c < 5) write_kv(buf ^ 1);
    }

    // ---- epilogue ----
#pragma unroll
    for (int qt = 0; qt < 2; ++qt) {
        float rl = __builtin_amdgcn_rcpf(l_run[qt]);
        size_t rowb = (seqbase + qi_base + qt * 16 + l15) * 1024 + h * 64;
#pragma unroll
        for (int dt = 0; dt < 4; ++dt) {
            int2 val = {pk_bf16(o[qt][dt][0] * rl, o[qt][dt][1] * rl),
                        pk_bf16(o[qt][dt][2] * rl, o[qt][dt][3] * rl)};
            *(int2*)(attn_out + rowb + dt * 16 + quad * 4) = val;
        }
    }
}

extern "C" void kernel_launch(void* const* d_in, const int* in_sizes, int n_in,
                              void* d_out, int out_size, void* d_ws, size_t ws_size,
                              hipStream_t stream) {
    const float* x     = (const float*)d_in[0];  // [4,4096,1024]
    const float* w_qkv = (const float*)d_in[1];  // [1024,3072]
    const float* w_out = (const float*)d_in[2];  // [1024,1024]
    float* out = (float*)d_out;                  // [4,4096,1024]

    unsigned short* xb    = (unsigned short*)d_ws;                 // 16384*1024
    unsigned short* wqkvT = xb    + (size_t)16384 * 1024;          // 3072*1024
    unsigned short* woutT = wqkvT + (size_t)3072 * 1024;           // 1024*1024
    unsigned short* qkv   = woutT + (size_t)1024 * 1024;           // 16384*3072
    unsigned short* attn  = qkv   + (size_t)16384 * 3072;          // 16384*1024

    cvt_x<<<16384, 256, 0, stream>>>(x, xb, 4194304);
    transpose_bf16<<<dim3(96, 32), 256, 0, stream>>>(w_qkv, wqkvT, 1024, 3072);
    transpose_bf16<<<dim3(32, 32), 256, 0, stream>>>(w_out, woutT, 1024, 1024);
    // QKV: M=16384, N=3072 -> 128x12 = 1536 tiles (1536 % 8 == 0)
    gemm_bt128<true><<<1536, 256, 0, stream>>>(xb, wqkvT, qkv, 16384, 3072, 1024, 12);
    attn_swin<<<dim3(32, 64), 256, 0, stream>>>(qkv, attn);
    // out-proj: M=16384, N=1024 -> 128x4 = 512 tiles (512 % 8 == 0)
    gemm_bt128<false><<<512, 256, 0, stream>>>(attn, woutT, out, 16384, 1024, 1024, 4);
}